// Round 1
// baseline (424.695 us; speedup 1.0000x reference)
//
#include <hip/hip_runtime.h>

typedef __attribute__((ext_vector_type(4))) short bf16x4;
typedef __attribute__((ext_vector_type(8))) short bf16x8;
typedef __attribute__((ext_vector_type(16))) float f32x16;
typedef __attribute__((ext_vector_type(2))) float f32x2;
typedef __attribute__((ext_vector_type(4))) unsigned int u32x4;

__device__ __forceinline__ unsigned short f2bf(float f) {
    unsigned int u = __builtin_bit_cast(unsigned int, f);
    u += 0x7fffu + ((u >> 16) & 1u);   // RNE (inputs are finite normals)
    return (unsigned short)(u >> 16);
}

#define PA 196   // lds_a pitch in bf16 elems: 196*2B=392B -> 98 dwords, 98%32=2 -> conflict-free-ish

// GEMM: z_partial[b] = feats[:, Kslice(b)] @ W[Kslice(b), :]
// feats computed on the fly from x via Rtot (3x3) along the c-axis.
// Block b owns inner-offset range p in [60b, 60b+60); iterates 4 slabs (i,chunk),
// each slab = 3 c3-outputs of 64 virtual-k (60 real + 4 pad) = 192 vk; total vK=768.
// 1024 threads = 16 waves (4x4 wave grid, 64x64 output tile per wave) for latency hiding.
__global__ __launch_bounds__(1024) void gemm_kernel(
    const float* __restrict__ x,
    const float* __restrict__ rw, const float* __restrict__ sw, const float* __restrict__ cw,
    const float* __restrict__ W,
    const float* __restrict__ Rr, const float* __restrict__ Rs, const float* __restrict__ Rc,
    float* __restrict__ P)
{
    __shared__ unsigned short lds_a[256 * PA];      // 100352 B, bf16 feats [n][vk]
    __shared__ unsigned int   lds_b[2][16 * 256];   // 2 x 16KB: packed bf16 pairs [vk2][d]

    const int tid = threadIdx.x;
    const int blk = blockIdx.x;
    const int p0 = blk * 60;

    // ---- Rtot = (R_rotate*rw) @ (R_shear*sw) @ (R_scale*cw), row-major [c][d] ----
    float Ar[9], Br[9], Cr[9], T1[9], RT[9];
    #pragma unroll
    for (int e = 0; e < 9; ++e) {
        Ar[e] = Rr[e] * rw[e];
        Br[e] = Rs[e] * sw[e];
        Cr[e] = Rc[e] * cw[e];
    }
    #pragma unroll
    for (int r = 0; r < 3; ++r)
        #pragma unroll
        for (int c = 0; c < 3; ++c)
            T1[r*3+c] = Ar[r*3+0]*Br[0*3+c] + Ar[r*3+1]*Br[1*3+c] + Ar[r*3+2]*Br[2*3+c];
    #pragma unroll
    for (int r = 0; r < 3; ++r)
        #pragma unroll
        for (int c = 0; c < 3; ++c)
            RT[r*3+c] = T1[r*3+0]*Cr[0*3+c] + T1[r*3+1]*Cr[1*3+c] + T1[r*3+2]*Cr[2*3+c];

    // ---- zero A pads once (cols c3*64+60..63 per row); B pads are zeroed inline ----
    if (tid < 256) {
        bf16x4 zz = (bf16x4)0;
        #pragma unroll
        for (int c3 = 0; c3 < 3; ++c3)
            *((bf16x4*)&lds_a[tid*PA + c3*64 + 60]) = zz;   // byte addr % 8 == 0
    }

    const int w  = tid >> 6, l = tid & 63;
    const int lm = l & 31,  lh = l >> 5;
    const int m0 = (w >> 2) * 64;     // 4 wave-rows
    const int d0 = (w & 3) * 64;      // 4 wave-cols

    f32x16 acc[2][2];
    #pragma unroll
    for (int fm = 0; fm < 2; ++fm)
        #pragma unroll
        for (int fd = 0; fd < 2; ++fd)
            acc[fm][fd] = (f32x16)0.0f;

    for (int s = 0; s < 4; ++s) {
        const int i = s >> 1, chunk = s & 1;
        // element offset of (n=0, c'=0, pl=0) in both x and W-row space:
        const long kbase = (long)i * 90000 + (long)chunk * 45000 + p0;
        const float* xs = x + kbase;

        // ---- issue W loads for sub-tile 0 (overlaps A staging) ----
        f32x2 L0[2], L1[2];
        int bd[2], bvk2[2];
        #pragma unroll
        for (int jj = 0; jj < 2; ++jj) {
            int item = jj*1024 + tid;
            int vk2l = item >> 7, dp = item & 127;
            int vk = vk2l*2;               // sub-tile 0
            int c3 = vk >> 6, pl = vk & 63;
            bd[jj] = dp*2; bvk2[jj] = vk2l;
            L0[jj] = (f32x2){0.f,0.f}; L1[jj] = (f32x2){0.f,0.f};
            if (pl < 60) {
                const float* wr = W + (kbase + (long)c3*15000 + pl)*256 + dp*2;
                L0[jj] = *(const f32x2*)wr;
                L1[jj] = *(const f32x2*)(wr + 256);
            }
        }

        // ---- A stage: read x once, emit all 3 transformed c-outputs as bf16 ----
        #pragma unroll 5
        for (int j = 0; j < 15; ++j) {
            int q = j*1024 + tid;                        // 15360 (n,pl) pairs
            int n = (int)(((unsigned)q * 34953u) >> 21); // q/60 (exact for q<15360)
            int pl = q - n*60;
            const float* px = xs + (long)n*180000 + pl;
            float x0 = px[0], x1 = px[15000], x2 = px[30000];
            float f0 = x0*RT[0] + x1*RT[3] + x2*RT[6];
            float f1 = x0*RT[1] + x1*RT[4] + x2*RT[7];
            float f2 = x0*RT[2] + x1*RT[5] + x2*RT[8];
            int a = n*PA + pl;
            lds_a[a      ] = f2bf(f0);
            lds_a[a +  64] = f2bf(f1);
            lds_a[a + 128] = f2bf(f2);
        }

        // ---- pack + write B sub-tile 0 ----
        #pragma unroll
        for (int jj = 0; jj < 2; ++jj) {
            unsigned int lo = (unsigned int)f2bf(L0[jj].x) | ((unsigned int)f2bf(L1[jj].x) << 16);
            unsigned int hi = (unsigned int)f2bf(L0[jj].y) | ((unsigned int)f2bf(L1[jj].y) << 16);
            unsigned int* pb = &lds_b[0][bvk2[jj]*256 + bd[jj]];
            pb[0] = lo; pb[1] = hi;
        }
        __syncthreads();

        // ---- 6 sub-steps of 32 vk, B double-buffered ----
        for (int t = 0; t < 6; ++t) {
            f32x2 M0[2], M1[2];
            int cd[2], cvk2[2];
            const bool have = (t < 5);
            if (have) {
                #pragma unroll
                for (int jj = 0; jj < 2; ++jj) {
                    int item = jj*1024 + tid;
                    int vk2l = item >> 7, dp = item & 127;
                    int vk = (t+1)*32 + vk2l*2;
                    int c3 = vk >> 6, pl = vk & 63;
                    cd[jj] = dp*2; cvk2[jj] = vk2l;
                    M0[jj] = (f32x2){0.f,0.f}; M1[jj] = (f32x2){0.f,0.f};
                    if (pl < 60) {
                        const float* wr = W + (kbase + (long)c3*15000 + pl)*256 + dp*2;
                        M0[jj] = *(const f32x2*)wr;
                        M1[jj] = *(const f32x2*)(wr + 256);
                    }
                }
            }

            const unsigned int* bbuf = lds_b[t & 1];
            #pragma unroll
            for (int kk = 0; kk < 2; ++kk) {
                int vk0 = t*32 + kk*16;
                int kb = vk0 + lh*8;
                bf16x8 af[2];
                #pragma unroll
                for (int fm = 0; fm < 2; ++fm) {
                    const unsigned short* pa = &lds_a[(m0 + fm*32 + lm)*PA + kb];
                    bf16x4 alo = *(const bf16x4*)pa;         // ds_read_b64 (8B-aligned)
                    bf16x4 ahi = *(const bf16x4*)(pa + 4);
                    af[fm] = __builtin_shufflevector(alo, ahi, 0,1,2,3,4,5,6,7);
                }
                #pragma unroll
                for (int fd = 0; fd < 2; ++fd) {
                    int db = d0 + fd*32 + lm;
                    int v2 = kk*8 + lh*4;
                    u32x4 bw = { bbuf[(v2+0)*256 + db], bbuf[(v2+1)*256 + db],
                                 bbuf[(v2+2)*256 + db], bbuf[(v2+3)*256 + db] };
                    bf16x8 bfv = __builtin_bit_cast(bf16x8, bw);
                    #pragma unroll
                    for (int fm = 0; fm < 2; ++fm)
                        acc[fm][fd] = __builtin_amdgcn_mfma_f32_32x32x16_bf16(af[fm], bfv, acc[fm][fd], 0, 0, 0);
                }
            }

            if (have) {
                unsigned int* nb = &lds_b[(t+1) & 1][0];
                #pragma unroll
                for (int jj = 0; jj < 2; ++jj) {
                    unsigned int lo = (unsigned int)f2bf(M0[jj].x) | ((unsigned int)f2bf(M1[jj].x) << 16);
                    unsigned int hi = (unsigned int)f2bf(M0[jj].y) | ((unsigned int)f2bf(M1[jj].y) << 16);
                    unsigned int* pb = &nb[cvk2[jj]*256 + cd[jj]];
                    pb[0] = lo; pb[1] = hi;
                }
            }
            __syncthreads();
        }
    }

    // ---- write fp32 partial C tile ----
    float* Pb = P + (size_t)blk * 65536;
    #pragma unroll
    for (int fm = 0; fm < 2; ++fm)
        #pragma unroll
        for (int fd = 0; fd < 2; ++fd)
            #pragma unroll
            for (int r = 0; r < 16; ++r) {
                int row = m0 + fm*32 + (r & 3) + 8*(r >> 2) + 4*lh;
                int col = d0 + fd*32 + lm;
                Pb[row*256 + col] = acc[fm][fd][r];
            }
}

// Sum 250 partials + bias, write z twice to out, write zhat (row-normalized) to Z.
__global__ __launch_bounds__(1024) void reduce_kernel(
    const float* __restrict__ P, const float* __restrict__ bias,
    float* __restrict__ out, float* __restrict__ Z)
{
    __shared__ float sred[4][256];
    __shared__ float wsum[16];
    const int n = blockIdx.x;
    const int tid = threadIdx.x;
    const int sg = tid >> 8, d = tid & 255;

    const float* p = P + (size_t)n*256 + d;
    float z = 0.f;
    #pragma unroll 8
    for (int s = sg; s < 250; s += 4) z += p[(size_t)s * 65536];
    sred[sg][d] = z;
    __syncthreads();

    float zf = 0.f;
    if (sg == 0) zf = sred[0][d] + sred[1][d] + sred[2][d] + sred[3][d] + bias[d];
    float sq = zf * zf;
    #pragma unroll
    for (int off = 32; off > 0; off >>= 1) sq += __shfl_down(sq, off, 64);
    if ((tid & 63) == 0) wsum[tid >> 6] = sq;
    __syncthreads();
    if (sg == 0) {
        float tot = wsum[0] + wsum[1] + wsum[2] + wsum[3];  // waves 0..3 hold sg==0
        float inv = rsqrtf(tot);
        out[1 + n*256 + d]         = zf;
        out[1 + 65536 + n*256 + d] = zf;
        Z[n*256 + d] = zf * inv;
    }
}

// loss = 2 - (2/255)*(||S||^2/256 - 1), S = sum_n zhat_n
__global__ __launch_bounds__(1024) void loss_kernel(const float* __restrict__ Z, float* __restrict__ out)
{
    __shared__ float sp[4][256];
    __shared__ float w4[16];
    const int tid = threadIdx.x;
    const int g = tid >> 8, d = tid & 255;
    float S = 0.f;
    #pragma unroll 8
    for (int n = g*64; n < g*64 + 64; ++n) S += Z[n*256 + d];
    sp[g][d] = S;
    __syncthreads();
    float v = 0.f;
    if (g == 0) {
        S = sp[0][d] + sp[1][d] + sp[2][d] + sp[3][d];
        v = S * S;
    }
    #pragma unroll
    for (int off = 32; off > 0; off >>= 1) v += __shfl_down(v, off, 64);
    if ((tid & 63) == 0) w4[tid >> 6] = v;
    __syncthreads();
    if (tid == 0) {
        float tot = w4[0] + w4[1] + w4[2] + w4[3];
        out[0] = 2.0f - (2.0f / 255.0f) * (tot * (1.0f / 256.0f) - 1.0f);
    }
}

extern "C" void kernel_launch(void* const* d_in, const int* in_sizes, int n_in,
                              void* d_out, int out_size, void* d_ws, size_t ws_size,
                              hipStream_t stream)
{
    (void)in_sizes; (void)n_in; (void)out_size; (void)ws_size;
    const float* x  = (const float*)d_in[0];
    const float* rw = (const float*)d_in[1];
    const float* sw = (const float*)d_in[2];
    const float* cw = (const float*)d_in[3];
    const float* W  = (const float*)d_in[4];
    const float* bb = (const float*)d_in[5];
    const float* Rr = (const float*)d_in[6];
    const float* Rs = (const float*)d_in[7];
    const float* Rc = (const float*)d_in[8];
    float* out = (float*)d_out;
    float* P = (float*)d_ws;                        // 250 * 65536 fp32 partials
    float* Z = P + (size_t)250 * 65536;             // 65536 fp32 zhat

    gemm_kernel<<<250, 1024, 0, stream>>>(x, rw, sw, cw, W, Rr, Rs, Rc, P);
    reduce_kernel<<<256, 1024, 0, stream>>>(P, bb, out, Z);
    loss_kernel<<<1, 1024, 0, stream>>>(Z, out);
}

// Round 2
// 412.081 us; speedup vs baseline: 1.0306x; 1.0306x over previous
//
#include <hip/hip_runtime.h>

typedef __attribute__((ext_vector_type(4))) short bf16x4;
typedef __attribute__((ext_vector_type(8))) short bf16x8;
typedef __attribute__((ext_vector_type(16))) float f32x16;
typedef __attribute__((ext_vector_type(4))) float f32x4;
typedef __attribute__((ext_vector_type(4))) unsigned int u32x4;

__device__ __forceinline__ unsigned short f2bf(float f) {
    unsigned int u = __builtin_bit_cast(unsigned int, f);
    u += 0x7fffu + ((u >> 16) & 1u);   // RNE (inputs are finite normals)
    return (unsigned short)(u >> 16);
}

#define PA 196   // lds_a pitch in bf16 elems

// ---- W prefetch: load 2 rows x 4 cols (f32x4 pair) per item, 2 items/thread ----
// items: 16 vk2-rows x 64 d-quads = 1024; thread -> (jj*8 + tid>>6, tid&63)
#define ISSUE(RW, kb, sub) do { \
    _Pragma("unroll") \
    for (int jj_ = 0; jj_ < 2; ++jj_) { \
        const int vk2_ = jj_*8 + (tid >> 6); \
        const int vk_  = (sub)*32 + vk2_*2; \
        const int c3_  = vk_ >> 6, pl_ = vk_ & 63; \
        f32x4 q0_ = {0.f,0.f,0.f,0.f}, q1_ = {0.f,0.f,0.f,0.f}; \
        if (pl_ < 60) { \
            const float* wr_ = W + ((kb) + (long)c3_*15000 + pl_)*256 + (tid & 63)*4; \
            q0_ = *(const f32x4*)wr_; \
            q1_ = *(const f32x4*)(wr_ + 256); \
        } \
        RW[jj_*8+0]=q0_.x; RW[jj_*8+1]=q0_.y; RW[jj_*8+2]=q0_.z; RW[jj_*8+3]=q0_.w; \
        RW[jj_*8+4]=q1_.x; RW[jj_*8+5]=q1_.y; RW[jj_*8+6]=q1_.z; RW[jj_*8+7]=q1_.w; \
    } \
} while (0)

// pack (row vk, row vk+1) bf16 pairs for 4 consecutive d -> one ds_write_b128
#define PACK(RW, bufsel) do { \
    _Pragma("unroll") \
    for (int jj_ = 0; jj_ < 2; ++jj_) { \
        const int vk2_ = jj_*8 + (tid >> 6); \
        u32x4 pw_; \
        pw_.x = (unsigned)f2bf(RW[jj_*8+0]) | ((unsigned)f2bf(RW[jj_*8+4]) << 16); \
        pw_.y = (unsigned)f2bf(RW[jj_*8+1]) | ((unsigned)f2bf(RW[jj_*8+5]) << 16); \
        pw_.z = (unsigned)f2bf(RW[jj_*8+2]) | ((unsigned)f2bf(RW[jj_*8+6]) << 16); \
        pw_.w = (unsigned)f2bf(RW[jj_*8+3]) | ((unsigned)f2bf(RW[jj_*8+7]) << 16); \
        *((u32x4*)&lds_b[bufsel][vk2_*256 + (tid & 63)*4]) = pw_; \
    } \
} while (0)

// ---- A stage: 3840 quad-items (256 n x 15 pl-quads), f32x4 x-loads, ds_write_b64 ----
#define ASTAGE(kb) do { \
    const float* xs_ = x + (kb); \
    _Pragma("unroll 2") \
    for (int k_ = 0; k_ < 8; ++k_) { \
        const int it_ = k_*512 + tid; \
        if (it_ < 3840) { \
            const int n_  = (int)(((unsigned)it_ * 4370u) >> 16);  /* it/15 exact */ \
            const int pl_ = (it_ - n_*15) * 4; \
            const float* px_ = xs_ + (long)n_*180000 + pl_; \
            const f32x4 c0_ = *(const f32x4*)px_; \
            const f32x4 c1_ = *(const f32x4*)(px_ + 15000); \
            const f32x4 c2_ = *(const f32x4*)(px_ + 30000); \
            bf16x4 o0_, o1_, o2_; \
            _Pragma("unroll") \
            for (int e_ = 0; e_ < 4; ++e_) { \
                o0_[e_] = (short)f2bf(c0_[e_]*RT[0] + c1_[e_]*RT[3] + c2_[e_]*RT[6]); \
                o1_[e_] = (short)f2bf(c0_[e_]*RT[1] + c1_[e_]*RT[4] + c2_[e_]*RT[7]); \
                o2_[e_] = (short)f2bf(c0_[e_]*RT[2] + c1_[e_]*RT[5] + c2_[e_]*RT[8]); \
            } \
            const int a_ = n_*PA + pl_; \
            *(bf16x4*)&lds_a[a_      ] = o0_; \
            *(bf16x4*)&lds_a[a_ +  64] = o1_; \
            *(bf16x4*)&lds_a[a_ + 128] = o2_; \
        } \
    } \
} while (0)

#define MFMASTEP(jstep) do { \
    const unsigned int* bb_ = lds_b[(jstep) & 1]; \
    _Pragma("unroll") \
    for (int kk_ = 0; kk_ < 2; ++kk_) { \
        const int kb_ = (jstep)*32 + kk_*16 + lh*8; \
        bf16x8 af_[2]; \
        _Pragma("unroll") \
        for (int fm_ = 0; fm_ < 2; ++fm_) { \
            const unsigned short* pa_ = &lds_a[(m0 + fm_*32 + lm)*PA + kb_]; \
            bf16x4 alo_ = *(const bf16x4*)pa_; \
            bf16x4 ahi_ = *(const bf16x4*)(pa_ + 4); \
            af_[fm_] = __builtin_shufflevector(alo_, ahi_, 0,1,2,3,4,5,6,7); \
        } \
        _Pragma("unroll") \
        for (int fd_ = 0; fd_ < 4; ++fd_) { \
            const int db_ = d0 + fd_*32 + lm; \
            const int v2_ = kk_*8 + lh*4; \
            u32x4 bw_ = { bb_[(v2_+0)*256 + db_], bb_[(v2_+1)*256 + db_], \
                          bb_[(v2_+2)*256 + db_], bb_[(v2_+3)*256 + db_] }; \
            bf16x8 bv_ = __builtin_bit_cast(bf16x8, bw_); \
            _Pragma("unroll") \
            for (int fm_ = 0; fm_ < 2; ++fm_) \
                acc[fm_][fd_] = __builtin_amdgcn_mfma_f32_32x32x16_bf16(af_[fm_], bv_, acc[fm_][fd_], 0, 0, 0); \
        } \
    } \
} while (0)

// GEMM: z_partial[b] = feats[:, Kslice(b)] @ W[Kslice(b), :]
// 512 threads (8 waves, 2x2 wave grid, 64x128 per wave), depth-2 W prefetch:
// at step u issue loads(u+2) -> regs; MFMA(buf[u&1]); pack loads(u+1) -> buf[(u+1)&1]; barrier.
__global__ __launch_bounds__(512, 2) void gemm_kernel(
    const float* __restrict__ x,
    const float* __restrict__ rw, const float* __restrict__ sw, const float* __restrict__ cw,
    const float* __restrict__ W,
    const float* __restrict__ Rr, const float* __restrict__ Rs, const float* __restrict__ Rc,
    float* __restrict__ P)
{
    __shared__ unsigned short lds_a[256 * PA];      // 100352 B, bf16 feats [n][vk]
    __shared__ unsigned int   lds_b[2][16 * 256];   // 2 x 16KB: packed bf16 pairs [vk2][d]

    const int tid = threadIdx.x;
    const int blk = blockIdx.x;
    const int p0 = blk * 60;

    // ---- Rtot = (R_rotate*rw) @ (R_shear*sw) @ (R_scale*cw), row-major [c][d] ----
    float Ar[9], Br[9], Cr[9], T1[9], RT[9];
    #pragma unroll
    for (int e = 0; e < 9; ++e) {
        Ar[e] = Rr[e] * rw[e];
        Br[e] = Rs[e] * sw[e];
        Cr[e] = Rc[e] * cw[e];
    }
    #pragma unroll
    for (int r = 0; r < 3; ++r)
        #pragma unroll
        for (int c = 0; c < 3; ++c)
            T1[r*3+c] = Ar[r*3+0]*Br[0*3+c] + Ar[r*3+1]*Br[1*3+c] + Ar[r*3+2]*Br[2*3+c];
    #pragma unroll
    for (int r = 0; r < 3; ++r)
        #pragma unroll
        for (int c = 0; c < 3; ++c)
            RT[r*3+c] = T1[r*3+0]*Cr[0*3+c] + T1[r*3+1]*Cr[1*3+c] + T1[r*3+2]*Cr[2*3+c];

    // ---- zero A pads once (cols c3*64+60..63 per row) ----
    if (tid < 256) {
        bf16x4 zz = (bf16x4)0;
        #pragma unroll
        for (int c3 = 0; c3 < 3; ++c3)
            *((bf16x4*)&lds_a[tid*PA + c3*64 + 60]) = zz;
    }

    const int w  = tid >> 6, l = tid & 63;
    const int lm = l & 31,  lh = l >> 5;
    const int m0 = (w >> 1) * 64;     // 4 wave-rows
    const int d0 = (w & 1) * 128;     // 2 wave-cols

    f32x16 acc[2][4];
    #pragma unroll
    for (int fm = 0; fm < 2; ++fm)
        #pragma unroll
        for (int fd = 0; fd < 4; ++fd)
            acc[fm][fd] = (f32x16)0.0f;

    float RWa[16], RWb[16];

    // ---- prologue: B(0),B(1) in flight; A-stage slab 0 under B(0) latency ----
    ISSUE(RWa, (long)p0, 0);
    ASTAGE((long)p0);
    ISSUE(RWb, (long)p0, 1);
    PACK(RWa, 0);
    __syncthreads();

    for (int slab = 0; slab < 4; ++slab) {
        const long kbase = (long)slab * 45000 + p0;   // slab*45000 == i*90000+chunk*45000
        const long kbnxt = kbase + 45000;
        #pragma unroll
        for (int j = 0; j < 6; ++j) {
            // issue loads for global step u+2 (u = slab*6+j); reg set parity = j&1
            if (j < 4) {
                if (j & 1) ISSUE(RWb, kbase, j+2);
                else       ISSUE(RWa, kbase, j+2);
            } else if (slab < 3) {
                if (j & 1) ISSUE(RWb, kbnxt, j-4);
                else       ISSUE(RWa, kbnxt, j-4);
            }
            // A-stage for this slab (slab 0 done in prologue); W loads fly underneath
            if (j == 0 && slab > 0) {
                ASTAGE(kbase);
                __syncthreads();
            }
            MFMASTEP(j);
            // pack B(u+1) from the other reg set into the other LDS buffer
            if (j < 5) {
                if (j & 1) PACK(RWa, ((j+1)&1));
                else       PACK(RWb, ((j+1)&1));
            } else if (slab < 3) {
                PACK(RWa, 0);
            }
            __syncthreads();
        }
    }

    // ---- write fp32 partial C tile ----
    float* Pb = P + (size_t)blk * 65536;
    #pragma unroll
    for (int fm = 0; fm < 2; ++fm)
        #pragma unroll
        for (int fd = 0; fd < 4; ++fd)
            #pragma unroll
            for (int r = 0; r < 16; ++r) {
                int row = m0 + fm*32 + (r & 3) + 8*(r >> 2) + 4*lh;
                int col = d0 + fd*32 + lm;
                Pb[row*256 + col] = acc[fm][fd][r];
            }
}

// Sum 250 partials + bias, write z twice to out, write zhat (row-normalized) to Z.
__global__ __launch_bounds__(1024) void reduce_kernel(
    const float* __restrict__ P, const float* __restrict__ bias,
    float* __restrict__ out, float* __restrict__ Z)
{
    __shared__ float sred[4][256];
    __shared__ float wsum[16];
    const int n = blockIdx.x;
    const int tid = threadIdx.x;
    const int sg = tid >> 8, d = tid & 255;

    const float* p = P + (size_t)n*256 + d;
    float z = 0.f;
    #pragma unroll 8
    for (int s = sg; s < 250; s += 4) z += p[(size_t)s * 65536];
    sred[sg][d] = z;
    __syncthreads();

    float zf = 0.f;
    if (sg == 0) zf = sred[0][d] + sred[1][d] + sred[2][d] + sred[3][d] + bias[d];
    float sq = zf * zf;
    #pragma unroll
    for (int off = 32; off > 0; off >>= 1) sq += __shfl_down(sq, off, 64);
    if ((tid & 63) == 0) wsum[tid >> 6] = sq;
    __syncthreads();
    if (sg == 0) {
        float tot = wsum[0] + wsum[1] + wsum[2] + wsum[3];  // waves 0..3 hold sg==0
        float inv = rsqrtf(tot);
        out[1 + n*256 + d]         = zf;
        out[1 + 65536 + n*256 + d] = zf;
        Z[n*256 + d] = zf * inv;
    }
}

// loss = 2 - (2/255)*(||S||^2/256 - 1), S = sum_n zhat_n
__global__ __launch_bounds__(1024) void loss_kernel(const float* __restrict__ Z, float* __restrict__ out)
{
    __shared__ float sp[4][256];
    __shared__ float w4[16];
    const int tid = threadIdx.x;
    const int g = tid >> 8, d = tid & 255;
    float S = 0.f;
    #pragma unroll 8
    for (int n = g*64; n < g*64 + 64; ++n) S += Z[n*256 + d];
    sp[g][d] = S;
    __syncthreads();
    float v = 0.f;
    if (g == 0) {
        S = sp[0][d] + sp[1][d] + sp[2][d] + sp[3][d];
        v = S * S;
    }
    #pragma unroll
    for (int off = 32; off > 0; off >>= 1) v += __shfl_down(v, off, 64);
    if ((tid & 63) == 0) w4[tid >> 6] = v;
    __syncthreads();
    if (tid == 0) {
        float tot = w4[0] + w4[1] + w4[2] + w4[3];
        out[0] = 2.0f - (2.0f / 255.0f) * (tot * (1.0f / 256.0f) - 1.0f);
    }
}

extern "C" void kernel_launch(void* const* d_in, const int* in_sizes, int n_in,
                              void* d_out, int out_size, void* d_ws, size_t ws_size,
                              hipStream_t stream)
{
    (void)in_sizes; (void)n_in; (void)out_size; (void)ws_size;
    const float* x  = (const float*)d_in[0];
    const float* rw = (const float*)d_in[1];
    const float* sw = (const float*)d_in[2];
    const float* cw = (const float*)d_in[3];
    const float* W  = (const float*)d_in[4];
    const float* bb = (const float*)d_in[5];
    const float* Rr = (const float*)d_in[6];
    const float* Rs = (const float*)d_in[7];
    const float* Rc = (const float*)d_in[8];
    float* out = (float*)d_out;
    float* P = (float*)d_ws;                        // 250 * 65536 fp32 partials
    float* Z = P + (size_t)250 * 65536;             // 65536 fp32 zhat

    gemm_kernel<<<250, 512, 0, stream>>>(x, rw, sw, cw, W, Rr, Rs, Rc, P);
    reduce_kernel<<<256, 1024, 0, stream>>>(P, bb, out, Z);
    loss_kernel<<<1, 1024, 0, stream>>>(Z, out);
}